// Round 1
// baseline (1493.605 us; speedup 1.0000x reference)
//
#include <hip/hip_runtime.h>

// Forest-Ruth symplectic integrator, B=32768, D=512, K=64, 4 steps.
// Layout: one 1024-thread block owns 64 rows for the whole integration.
//   v  : LDS [64][516] (padded, conflict-free b128 row reads)
//   h  : LDS [64][65]
//   x, force : registers, thread (w,l) owns (row=l, cols [32w,32w+32))
// GEMMs use lane=row so U/W operands are wave-uniform -> s_load + SGPR-FMA.

#define D_DIM 512
#define ROWS  64
#define VSTR  516
#define HSTR  65
#define NTH   1024
#define LDS_BYTES ((ROWS*VSTR + ROWS*HSTR) * 4)   // 148736 B

__device__ __forceinline__ float wrap_torus(float y) {
    // matches np: (y + pi) % (2pi) - pi, for y in (-2pi, 2*2pi)
    const float PI_F  = 3.14159265358979323846f;   // 0x40490FDB
    const float TPI_F = 6.28318530717958647692f;   // 0x40C90FDB == 2*PI_F
    float t = y + PI_F;
    if (t >= TPI_F) t -= TPI_F;        // exact (Sterbenz) == fmod
    else if (t < 0.0f) t += TPI_F;     // matches np.mod sign fixup
    return t - PI_F;
}

__global__ __launch_bounds__(NTH) void fr_kernel(
    const float* __restrict__ xin, const float* __restrict__ vin,
    const float* __restrict__ fin, const float* __restrict__ Um,
    const float* __restrict__ Wm, float* __restrict__ xout,
    float* __restrict__ vout)
{
    extern __shared__ float lds[];
    float* vs = lds;                 // [64][516]
    float* hs = lds + ROWS * VSTR;   // [64][65]

    const int t = threadIdx.x;
    const int l = t & 63;
    const int w = __builtin_amdgcn_readfirstlane(t >> 6);  // wave id, uniform

    // coefficients: double like python, cast to f32 like numpy scalar*f32-array
    const double theta = 1.0 / (2.0 - 1.2599210498948732);  // 2**(1/3)
    const float c1dt = (float)(theta * 0.5 * 0.01);
    const float c2dt = (float)((1.0 - theta) * 0.5 * 0.01);
    const float d1dt = (float)(theta * 0.01);
    const float d2dt = (float)((1.0 - 2.0 * theta) * 0.01);

    const int rowBase = (int)blockIdx.x * ROWS;
    const int colBase = w << 5;   // 32 cols per wave

    // ---- load x, force slices (row l, cols [colBase, colBase+32)) into regs
    float xv[32], fv[32];
    {
        const float* xg = xin + (size_t)(rowBase + l) * D_DIM + colBase;
        const float* fg = fin + (size_t)(rowBase + l) * D_DIM + colBase;
        #pragma unroll
        for (int q = 0; q < 8; ++q) {
            float4 a = *(const float4*)(xg + 4*q);
            float4 b = *(const float4*)(fg + 4*q);
            xv[4*q+0]=a.x; xv[4*q+1]=a.y; xv[4*q+2]=a.z; xv[4*q+3]=a.w;
            fv[4*q+0]=b.x; fv[4*q+1]=b.y; fv[4*q+2]=b.z; fv[4*q+3]=b.w;
        }
    }
    // ---- stage v into LDS, coalesced global reads
    {
        const float* vg = vin + (size_t)rowBase * D_DIM;
        #pragma unroll
        for (int it = 0; it < 8; ++it) {
            int flat = it*4096 + t*4;
            float4 val = *(const float4*)(vg + flat);
            int row = flat >> 9, col = flat & 511;
            *(float4*)(vs + row*VSTR + col) = val;
        }
    }
    __syncthreads();

    // ---- x1 = wrap(x + c1dt * v0)
    {
        const float* vsl = vs + l*VSTR + colBase;
        #pragma unroll
        for (int q = 0; q < 8; ++q) {
            float4 v4 = *(const float4*)(vsl + 4*q);
            xv[4*q+0] = wrap_torus(xv[4*q+0] + c1dt*v4.x);
            xv[4*q+1] = wrap_torus(xv[4*q+1] + c1dt*v4.y);
            xv[4*q+2] = wrap_torus(xv[4*q+2] + c1dt*v4.z);
            xv[4*q+3] = wrap_torus(xv[4*q+3] + c1dt*v4.w);
        }
    }

    const int kg = (w & 3) << 4;   // k-group start  (16 k's)
    const int dg = (w >> 2) << 7;  // d-group start (128 d's)

    #pragma unroll 1
    for (int step = 0; step < 4; ++step) {
      for (int sub = 0; sub < 3; ++sub) {
        const float ddt = (sub == 1) ? d2dt : d1dt;          // D1,D2,D3=D1
        const float xc  = (sub == 2) ? c1dt : c2dt;          // C2,C3=C2,C4=C1
        const bool dbl  = (sub == 2) && (step < 3);          // fuse next x1

        __syncthreads();                       // v stable, prev h-reads done
        for (int i = t; i < ROWS*HSTR; i += NTH) hs[i] = 0.0f;
        __syncthreads();

        // ---- GEMM1 partials: h[l][kg..kg+16) over d in [dg, dg+128)
        {
            float hp[16];
            #pragma unroll
            for (int i = 0; i < 16; ++i) hp[i] = 0.0f;
            const float* vrow = vs + l*VSTR + dg;
            for (int dc = 0; dc < 128; dc += 4) {
                float4 vf = *(const float4*)(vrow + dc);
                float vfa[4] = {vf.x, vf.y, vf.z, vf.w};
                const float* ub = Um + (dg + dc)*64 + kg;    // uniform addr
                #pragma unroll
                for (int j = 0; j < 4; ++j) {
                    #pragma unroll
                    for (int ki = 0; ki < 16; ++ki)
                        hp[ki] = fmaf(vfa[j], ub[j*64 + ki], hp[ki]);
                }
            }
            #pragma unroll
            for (int i = 0; i < 16; ++i)
                atomicAdd(hs + l*HSTR + kg + i, hp[i]);      // ds_add_f32
        }
        __syncthreads();

        // ---- GEMM2: christ[l][colBase..+32) + fused v/x update epilogue
        {
            float acc[32];
            #pragma unroll
            for (int i = 0; i < 32; ++i) acc[i] = 0.0f;
            const float* hrow = hs + l*HSTR;
            for (int k = 0; k < 64; ++k) {
                float hvv = hrow[k];
                float gk = hvv * hvv;
                const float* wb = Wm + (k << 9) + colBase;   // uniform addr
                #pragma unroll
                for (int j = 0; j < 32; ++j)
                    acc[j] = fmaf(gk, wb[j], acc[j]);
            }
            float* vsl = vs + l*VSTR + colBase;
            #pragma unroll
            for (int q = 0; q < 8; ++q) {
                float4 vo = *(const float4*)(vsl + 4*q);
                float va[4] = {vo.x, vo.y, vo.z, vo.w};
                #pragma unroll
                for (int c = 0; c < 4; ++c) {
                    int j = 4*q + c;
                    float a  = fv[j] - acc[j];     // -christ + force
                    float vn = va[c] + ddt * a;
                    va[c] = vn;
                    float xn = wrap_torus(xv[j] + xc * vn);
                    if (dbl) xn = wrap_torus(xn + c1dt * vn);  // next step's x1
                    xv[j] = xn;
                }
                float4 vv; vv.x=va[0]; vv.y=va[1]; vv.z=va[2]; vv.w=va[3];
                *(float4*)(vsl + 4*q) = vv;
            }
        }
      }
    }

    __syncthreads();
    // ---- store cx (registers)
    {
        float* xo = xout + (size_t)(rowBase + l) * D_DIM + colBase;
        #pragma unroll
        for (int q = 0; q < 8; ++q) {
            float4 s;
            s.x=xv[4*q+0]; s.y=xv[4*q+1]; s.z=xv[4*q+2]; s.w=xv[4*q+3];
            *(float4*)(xo + 4*q) = s;
        }
    }
    // ---- store cv (coalesced from LDS)
    {
        float* vo = vout + (size_t)rowBase * D_DIM;
        #pragma unroll
        for (int it = 0; it < 8; ++it) {
            int flat = it*4096 + t*4;
            int row = flat >> 9, col = flat & 511;
            *(float4*)(vo + flat) = *(const float4*)(vs + row*VSTR + col);
        }
    }
}

extern "C" void kernel_launch(void* const* d_in, const int* in_sizes, int n_in,
                              void* d_out, int out_size, void* d_ws, size_t ws_size,
                              hipStream_t stream) {
    const float* x = (const float*)d_in[0];
    const float* v = (const float*)d_in[1];
    const float* f = (const float*)d_in[2];
    const float* U = (const float*)d_in[3];
    const float* W = (const float*)d_in[4];
    // d_in[5] = steps (constant 4, baked in)

    float* xout = (float*)d_out;
    float* vout = xout + (size_t)32768 * 512;

    hipFuncSetAttribute(reinterpret_cast<const void*>(fr_kernel),
                        hipFuncAttributeMaxDynamicSharedMemorySize, LDS_BYTES);
    fr_kernel<<<512, NTH, LDS_BYTES, stream>>>(x, v, f, U, W, xout, vout);
}

// Round 2
// 1224.901 us; speedup vs baseline: 1.2194x; 1.2194x over previous
//
#include <hip/hip_runtime.h>

// Forest-Ruth integrator via bf16x3-split MFMA (32x32x16), B=32768, D=512, K=64.
// Block = 32 rows, 512 threads (8 waves), grid 1024. 1 block/CU (LDS-bound).
// U/W: prep kernel splits fp32 -> bf16 hi/lo, swizzled to MFMA B-frag layout in
// d_ws; main kernel holds them in VGPRs for the whole run (128 VGPRs).
// v/x state in registers (MFMA C/D layout, verified: col=lane&31,
// row=(reg&3)+8*(reg>>2)+4*(lane>>5)). v round-trips LDS in A-frag layout.

#define NTH 512

// LDS word-offsets (4B words)
#define VF0 0          // v-frag plane j0..3 : [32 kstep][64 lane][4 words]
#define VF1 8192       // v-frag plane j4..7
#define GF0 16384      // g-frag plane j0..3 : [4 kstep][64 lane][4 words]
#define GF1 17408      // g-frag plane j4..7
#define HB  18432      // h buffer fp32 [32][68]
#define FB  20608      // f buffer fp32 [32][516]
#define LDS_WORDS 37120
#define LDS_BYTES (LDS_WORDS*4)   // 148480 B

typedef __attribute__((ext_vector_type(8))) short short8;
typedef __attribute__((ext_vector_type(16))) float float16;

__device__ __forceinline__ float wrap_torus(float y) {
    const float PI_F  = 3.14159265358979323846f;
    const float TPI_F = 6.28318530717958647692f;
    float t = y + PI_F;
    if (t >= TPI_F) t -= TPI_F;
    else if (t < 0.0f) t += TPI_F;
    return t - PI_F;
}

__device__ __forceinline__ void split2(float v, unsigned short& hi, unsigned short& lo) {
    unsigned u = __float_as_uint(v);
    unsigned h = (u + 0x7fffu + ((u >> 16) & 1u)) >> 16;    // RNE to bf16
    hi = (unsigned short)h;
    float hf = __uint_as_float(h << 16);
    float r = v - hf;                                        // exact
    unsigned u2 = __float_as_uint(r);
    unsigned l = (u2 + 0x7fffu + ((u2 >> 16) & 1u)) >> 16;
    lo = (unsigned short)l;
}

__device__ __forceinline__ unsigned pack_split(float v) {
    unsigned short hi, lo;
    split2(v, hi, lo);
    return (((unsigned)hi) << 16) | (unsigned)lo;
}

__device__ __forceinline__ void unpack_frag(uint4 l4, uint4 h4, short8& fhi, short8& flo) {
    fhi[0]=(short)(l4.x>>16); flo[0]=(short)(l4.x&0xffffu);
    fhi[1]=(short)(l4.y>>16); flo[1]=(short)(l4.y&0xffffu);
    fhi[2]=(short)(l4.z>>16); flo[2]=(short)(l4.z&0xffffu);
    fhi[3]=(short)(l4.w>>16); flo[3]=(short)(l4.w&0xffffu);
    fhi[4]=(short)(h4.x>>16); flo[4]=(short)(h4.x&0xffffu);
    fhi[5]=(short)(h4.y>>16); flo[5]=(short)(h4.y&0xffffu);
    fhi[6]=(short)(h4.z>>16); flo[6]=(short)(h4.z&0xffffu);
    fhi[7]=(short)(h4.w>>16); flo[7]=(short)(h4.w&0xffffu);
}

// ---- prep: split U, W to bf16 hi/lo in MFMA B-frag swizzled layout in d_ws.
// U frag (nt1,ks4,c): B[k][n]: n = 32*nt1 + (lane&31), d = 128*ks4+16*c+8*(lane>>5)+j
// W frag (nt,kk):     B[k][n]: n = 32*nt  + (lane&31), k = 16*kk+8*(lane>>5)+j
__global__ void fr_prep(const float* __restrict__ Um, const float* __restrict__ Wm,
                        unsigned short* __restrict__ usw, unsigned short* __restrict__ wsw) {
    int tid = blockIdx.x * 256 + threadIdx.x;   // 8192 total
    int lane = tid & 63;
    if (tid < 4096) {
        int c   = (tid >> 6) & 7;
        int ks4 = (tid >> 9) & 3;
        int nt1 = (tid >> 11) & 1;
        int fbase = (((nt1 * 4 + ks4) * 8 + c) * 2) * 512;   // ushort units
        #pragma unroll
        for (int j = 0; j < 8; ++j) {
            int d = 128 * ks4 + 16 * c + 8 * (lane >> 5) + j;
            int n = 32 * nt1 + (lane & 31);
            unsigned short hi, lo;
            split2(Um[d * 64 + n], hi, lo);
            usw[fbase + lane * 8 + j] = hi;
            usw[fbase + 512 + lane * 8 + j] = lo;
        }
    } else {
        int id = tid - 4096;
        lane = id & 63;
        int kk = (id >> 6) & 3;
        int nt = (id >> 8) & 15;
        int fbase = ((nt * 4 + kk) * 2) * 512;
        #pragma unroll
        for (int j = 0; j < 8; ++j) {
            int k = 16 * kk + 8 * (lane >> 5) + j;
            int n = 32 * nt + (lane & 31);
            unsigned short hi, lo;
            split2(Wm[k * 512 + n], hi, lo);
            wsw[fbase + lane * 8 + j] = hi;
            wsw[fbase + 512 + lane * 8 + j] = lo;
        }
    }
}

__global__ __launch_bounds__(NTH, 2) void fr_mfma(
    const float* __restrict__ xin, const float* __restrict__ vin,
    const float* __restrict__ fin,
    const short8* __restrict__ usw, const short8* __restrict__ wsw,
    float* __restrict__ xout, float* __restrict__ vout)
{
    extern __shared__ float lds[];
    unsigned int* ldsu = (unsigned int*)lds;

    const int t = threadIdx.x;
    const int lane = t & 63;
    const int w = __builtin_amdgcn_readfirstlane(t >> 6);    // 0..7
    const int nt1 = w & 1;       // GEMM1 h-col tile
    const int ks4 = w >> 1;      // GEMM1 k-split (d range 128*ks4..+128)
    const int rhalf = lane >> 5;
    const int R0 = (int)blockIdx.x * 32;

    const double theta = 1.0 / (2.0 - 1.2599210498948732);
    const float c1dt = (float)(theta * 0.5 * 0.01);
    const float c2dt = (float)((1.0 - theta) * 0.5 * 0.01);
    const float d1dt = (float)(theta * 0.01);
    const float d2dt = (float)((1.0 - 2.0 * theta) * 0.01);

    // ---- permanent operand fragments
    short8 Uhi[8], Ulo[8], Whi[2][4], Wlo[2][4];
    {
        int ub = ((nt1 * 4 + ks4) * 8) * 2;   // frag index base (short8 units = 64 each)
        #pragma unroll
        for (int c = 0; c < 8; ++c) {
            Uhi[c] = usw[(ub + 2 * c + 0) * 64 + lane];
            Ulo[c] = usw[(ub + 2 * c + 1) * 64 + lane];
        }
        #pragma unroll
        for (int nt = 0; nt < 2; ++nt) {
            int wb = ((w * 2 + nt) * 4) * 2;
            #pragma unroll
            for (int kk = 0; kk < 4; ++kk) {
                Whi[nt][kk] = wsw[(wb + 2 * kk + 0) * 64 + lane];
                Wlo[nt][kk] = wsw[(wb + 2 * kk + 1) * 64 + lane];
            }
        }
    }

    // ---- state registers in C/D layout: col = 32*(2w+nt)+(lane&31),
    //      row = (r&3)+8*(r>>2)+4*rhalf
    float vst[2][16], xst[2][16];
    int cg[2];
    cg[0] = (w * 2 + 0) * 32 + (lane & 31);
    cg[1] = (w * 2 + 1) * 32 + (lane & 31);
    #pragma unroll
    for (int nt = 0; nt < 2; ++nt) {
        #pragma unroll
        for (int r = 0; r < 16; ++r) {
            int rrow = (r & 3) + 8 * (r >> 2) + 4 * rhalf;
            size_t idx = (size_t)(R0 + rrow) * 512 + cg[nt];
            vst[nt][r] = vin[idx];
            xst[nt][r] = xin[idx];
        }
    }

    // ---- stage f into LDS [32][516]
    {
        #pragma unroll
        for (int it = 0; it < 8; ++it) {
            int flat = it * 2048 + t * 4;
            float4 val = *(const float4*)(fin + (size_t)R0 * 512 + flat);
            int row = flat >> 9, col = flat & 511;
            *(float4*)(lds + FB + row * 516 + col) = val;
        }
    }

    // ---- x1 = wrap(x + c1dt*v)
    #pragma unroll
    for (int nt = 0; nt < 2; ++nt)
        #pragma unroll
        for (int r = 0; r < 16; ++r)
            xst[nt][r] = wrap_torus(xst[nt][r] + c1dt * vst[nt][r]);

    // ---- write v0 splits to vfrag; zero hbuf
    #pragma unroll
    for (int nt = 0; nt < 2; ++nt) {
        #pragma unroll
        for (int r = 0; r < 16; ++r) {
            int m = (r & 3) + 8 * (r >> 2) + 4 * rhalf;
            int d = cg[nt];
            unsigned p = pack_split(vst[nt][r]);
            int kst = d >> 4, lb = (d >> 3) & 1, j = d & 7;
            ldsu[((j >> 2) ? VF1 : VF0) + (kst * 64 + m + 32 * lb) * 4 + (j & 3)] = p;
        }
    }
    for (int i = t; i < 32 * 68; i += NTH) lds[HB + i] = 0.0f;

    #pragma unroll 1
    for (int sub = 0; sub < 12; ++sub) {
        const int idx3 = sub - (sub / 3) * 3;
        const float ddt = (idx3 == 1) ? d2dt : d1dt;
        const float xc  = (idx3 == 2) ? c1dt : c2dt;
        const bool dbl  = (idx3 == 2) && (sub != 11);

        __syncthreads();   // B0: vfrag writes + hbuf zero complete

        // ---- GEMM1: h-tile(nt1), d in [128*ks4, +128), 3-pass bf16x3
        float16 acc0, acc1;
        #pragma unroll
        for (int i = 0; i < 16; ++i) { acc0[i] = 0.0f; acc1[i] = 0.0f; }
        #pragma unroll
        for (int c = 0; c < 8; ++c) {
            int kst = ks4 * 8 + c;
            uint4 pl = *(const uint4*)&ldsu[VF0 + (kst * 64 + lane) * 4];
            uint4 ph = *(const uint4*)&ldsu[VF1 + (kst * 64 + lane) * 4];
            short8 Ahi, Alo;
            unpack_frag(pl, ph, Ahi, Alo);
            acc0 = __builtin_amdgcn_mfma_f32_32x32x16_bf16(Ahi, Uhi[c], acc0, 0, 0, 0);
            acc1 = __builtin_amdgcn_mfma_f32_32x32x16_bf16(Alo, Uhi[c], acc1, 0, 0, 0);
            acc1 = __builtin_amdgcn_mfma_f32_32x32x16_bf16(Ahi, Ulo[c], acc1, 0, 0, 0);
        }
        {
            int kcol = nt1 * 32 + (lane & 31);
            #pragma unroll
            for (int r = 0; r < 16; ++r) {
                int m = (r & 3) + 8 * (r >> 2) + 4 * rhalf;
                atomicAdd(&lds[HB + m * 68 + kcol], acc0[r] + acc1[r]);
            }
        }
        __syncthreads();   // B1: h complete

        // ---- g = h*h, split, write g-frags (4 elems/thread, one b128)
        {
            int grow = t >> 4;
            int k4 = (t & 15) * 4;
            float4 h4 = *(const float4*)&lds[HB + grow * 68 + k4];
            uint4 gp;
            gp.x = pack_split(h4.x * h4.x);
            gp.y = pack_split(h4.y * h4.y);
            gp.z = pack_split(h4.z * h4.z);
            gp.w = pack_split(h4.w * h4.w);
            int kst2 = k4 >> 4, lb2 = (k4 >> 3) & 1, jb = k4 & 7;
            *(uint4*)&ldsu[((jb >> 2) ? GF1 : GF0) + (kst2 * 64 + grow + 32 * lb2) * 4] = gp;
        }
        __syncthreads();   // B2: g-frags ready

        // ---- GEMM2: christ tiles 2w, 2w+1 over K=64
        float16 cA, cB;
        #pragma unroll
        for (int i = 0; i < 16; ++i) { cA[i] = 0.0f; cB[i] = 0.0f; }
        #pragma unroll
        for (int kk = 0; kk < 4; ++kk) {
            uint4 pl = *(const uint4*)&ldsu[GF0 + (kk * 64 + lane) * 4];
            uint4 ph = *(const uint4*)&ldsu[GF1 + (kk * 64 + lane) * 4];
            short8 Ahi, Alo;
            unpack_frag(pl, ph, Ahi, Alo);
            cA = __builtin_amdgcn_mfma_f32_32x32x16_bf16(Ahi, Whi[0][kk], cA, 0, 0, 0);
            cB = __builtin_amdgcn_mfma_f32_32x32x16_bf16(Ahi, Whi[1][kk], cB, 0, 0, 0);
            cA = __builtin_amdgcn_mfma_f32_32x32x16_bf16(Alo, Whi[0][kk], cA, 0, 0, 0);
            cB = __builtin_amdgcn_mfma_f32_32x32x16_bf16(Alo, Whi[1][kk], cB, 0, 0, 0);
            cA = __builtin_amdgcn_mfma_f32_32x32x16_bf16(Ahi, Wlo[0][kk], cA, 0, 0, 0);
            cB = __builtin_amdgcn_mfma_f32_32x32x16_bf16(Ahi, Wlo[1][kk], cB, 0, 0, 0);
        }

        // ---- epilogue: v += ddt*(f - christ); x = wrap(x + xc*v) (+ fused c1)
        #pragma unroll
        for (int nt = 0; nt < 2; ++nt) {
            #pragma unroll
            for (int r = 0; r < 16; ++r) {
                int m = (r & 3) + 8 * (r >> 2) + 4 * rhalf;
                float fv = lds[FB + m * 516 + cg[nt]];
                float christ = (nt == 0) ? cA[r] : cB[r];
                float vn = vst[nt][r] + ddt * (fv - christ);
                vst[nt][r] = vn;
                float xn = wrap_torus(xst[nt][r] + xc * vn);
                if (dbl) xn = wrap_torus(xn + c1dt * vn);
                xst[nt][r] = xn;
            }
        }

        // ---- write new v splits + zero hbuf for next substep
        if (sub != 11) {
            #pragma unroll
            for (int nt = 0; nt < 2; ++nt) {
                #pragma unroll
                for (int r = 0; r < 16; ++r) {
                    int m = (r & 3) + 8 * (r >> 2) + 4 * rhalf;
                    int d = cg[nt];
                    unsigned p = pack_split(vst[nt][r]);
                    int kst = d >> 4, lb = (d >> 3) & 1, j = d & 7;
                    ldsu[((j >> 2) ? VF1 : VF0) + (kst * 64 + m + 32 * lb) * 4 + (j & 3)] = p;
                }
            }
            for (int i = t; i < 32 * 68; i += NTH) lds[HB + i] = 0.0f;
        }
    }

    // ---- store outputs
    #pragma unroll
    for (int nt = 0; nt < 2; ++nt) {
        #pragma unroll
        for (int r = 0; r < 16; ++r) {
            int rrow = (r & 3) + 8 * (r >> 2) + 4 * rhalf;
            size_t idx = (size_t)(R0 + rrow) * 512 + cg[nt];
            xout[idx] = xst[nt][r];
            vout[idx] = vst[nt][r];
        }
    }
}

extern "C" void kernel_launch(void* const* d_in, const int* in_sizes, int n_in,
                              void* d_out, int out_size, void* d_ws, size_t ws_size,
                              hipStream_t stream) {
    const float* x = (const float*)d_in[0];
    const float* v = (const float*)d_in[1];
    const float* f = (const float*)d_in[2];
    const float* U = (const float*)d_in[3];
    const float* W = (const float*)d_in[4];

    float* xout = (float*)d_out;
    float* vout = xout + (size_t)32768 * 512;

    unsigned short* usw = (unsigned short*)d_ws;               // 128 KiB
    unsigned short* wsw = usw + 65536;                          // 128 KiB

    fr_prep<<<32, 256, 0, stream>>>(U, W, usw, wsw);

    hipFuncSetAttribute(reinterpret_cast<const void*>(fr_mfma),
                        hipFuncAttributeMaxDynamicSharedMemorySize, LDS_BYTES);
    fr_mfma<<<1024, NTH, LDS_BYTES, stream>>>(
        x, v, f, (const short8*)usw, (const short8*)wsw, xout, vout);
}